// Round 12
// baseline (109.835 us; speedup 1.0000x reference)
//
#include <hip/hip_runtime.h>

typedef __bf16 bf16;
typedef __bf16 bf16x8 __attribute__((ext_vector_type(8)));
typedef __bf16 bf16x4v __attribute__((ext_vector_type(4)));
typedef float  f32x4  __attribute__((ext_vector_type(4)));

#define NROWS 8192
#define DDIM  256
#define TAU_INV 2.0f
#define KAPPA 2.8853900817779268f   // TAU_INV * log2(e): A pre-scale so exp(s/tau) = exp2(acc)
#define LN2 0.6931471805599453f
#define EPS 1e-8f

#define AS1C(p) ((const __attribute__((address_space(1))) void*)(p))
#define AS3(p)  ((__attribute__((address_space(3))) void*)(p))

// ---------------- cast 4 weight matrices fp32 -> bf16 ----------------
__global__ __launch_bounds__(256) void cast4_kernel(
    const float* __restrict__ s0, const float* __restrict__ s1,
    const float* __restrict__ s2, const float* __restrict__ s3,
    bf16* __restrict__ dst) {
  const float* s = blockIdx.y == 0 ? s0 : blockIdx.y == 1 ? s1 : blockIdx.y == 2 ? s2 : s3;
  bf16* d = dst + (size_t)blockIdx.y * 65536;
  int i = blockIdx.x * 256 + threadIdx.x;
  f32x4 v = ((const f32x4*)s)[i];
  bf16x4v o;
  o[0] = (bf16)v[0]; o[1] = (bf16)v[1]; o[2] = (bf16)v[2]; o[3] = (bf16)v[3];
  ((bf16x4v*)d)[i] = o;
}

// ---------------- fused cast + 2-layer MLP + row-normalize (ct-split) ----------------
// grid (NROWS/64, 2), block 256 (4 waves). Wave w computes output cols
// [w*64, w*64+64) for ALL 64 rows. Weight fragments register-prefetched one
// ks ahead (global loads must never sit directly in front of their MFMA - r10).
__global__ __launch_bounds__(256, 1) void mlp_norm_kernel(
    const float* __restrict__ z1f, const float* __restrict__ z2f,
    const bf16* __restrict__ wq,
    const float* __restrict__ b1c, const float* __restrict__ b2c,
    const float* __restrict__ b1k, const float* __restrict__ b2k,
    bf16* __restrict__ outA, bf16* __restrict__ outB)
{
  const int view = blockIdx.y;
  const float* xf = view ? z2f : z1f;
  const bf16*  w1 = wq + (size_t)view * 131072;
  const bf16*  w2 = w1 + 65536;
  const float* b1 = view ? b1k : b1c;
  const float* b2 = view ? b2k : b2c;
  bf16* out = view ? outB : outA;
  const float osc = view ? 1.0f : KAPPA;

  __shared__ __align__(16) char xs[64 * 512];   // x rows, XOR-swizzled
  __shared__ __align__(16) char hs[64 * 512];   // h rows, XOR-swizzled
  __shared__ float sspart[4][64];

  const int tid  = threadIdx.x;
  const int lane = tid & 63;
  const int w    = tid >> 6;
  const int c    = lane & 15;
  const int g    = lane >> 4;
  const int r0   = blockIdx.x * 64;
  const int colw = w * 64;

  // fused cast: load f32, convert, swizzled ds_write
#pragma unroll
  for (int k = 0; k < 8; ++k) {
    int gid = k * 256 + tid;
    int row = gid >> 5, cg = gid & 31;
    const f32x4* p = (const f32x4*)(xf + (size_t)(r0 + row) * DDIM + cg * 8);
    f32x4 v0 = p[0], v1 = p[1];
    bf16x8 o;
    o[0] = (bf16)v0[0]; o[1] = (bf16)v0[1]; o[2] = (bf16)v0[2]; o[3] = (bf16)v0[3];
    o[4] = (bf16)v1[0]; o[5] = (bf16)v1[1]; o[6] = (bf16)v1[2]; o[7] = (bf16)v1[3];
    *(bf16x8*)(xs + row * 512 + ((cg * 16) ^ ((row & 7) << 4))) = o;
  }
  __syncthreads();

  float b1v[4], b2v[4];
#pragma unroll
  for (int ct = 0; ct < 4; ++ct) {
    b1v[ct] = b1[colw + ct * 16 + c];
    b2v[ct] = b2[colw + ct * 16 + c];
  }

  const int aswz = (c & 7) << 4;
  const bf16* w1base = w1 + (size_t)(colw + c) * DDIM + g * 8;  // + ct*16*DDIM + ks*32
  const bf16* w2base = w2 + (size_t)(colw + c) * DDIM + g * 8;

  f32x4 acc[4][4];                        // [ct][mt]
  const f32x4 fz = {0.f, 0.f, 0.f, 0.f};
#pragma unroll
  for (int ct = 0; ct < 4; ++ct)
#pragma unroll
    for (int mt = 0; mt < 4; ++mt) acc[ct][mt] = fz;

  // GEMM1: h_pre = x @ W1^T ; weights prefetched one ks ahead
  bf16x8 wcur[4], wnxt[4];
#pragma unroll
  for (int ct = 0; ct < 4; ++ct)
    wcur[ct] = *(const bf16x8*)(w1base + (size_t)ct * 16 * DDIM);
#pragma unroll
  for (int ks = 0; ks < 8; ++ks) {
    if (ks < 7) {
#pragma unroll
      for (int ct = 0; ct < 4; ++ct)
        wnxt[ct] = *(const bf16x8*)(w1base + (size_t)ct * 16 * DDIM + (ks + 1) * 32);
    }
    bf16x8 af[4];
#pragma unroll
    for (int mt = 0; mt < 4; ++mt)
      af[mt] = *(const bf16x8*)(xs + (mt * 16 + c) * 512 + ((ks * 64 + g * 16) ^ aswz));
#pragma unroll
    for (int ct = 0; ct < 4; ++ct)
#pragma unroll
      for (int mt = 0; mt < 4; ++mt)
        acc[ct][mt] = __builtin_amdgcn_mfma_f32_16x16x32_bf16(af[mt], wcur[ct], acc[ct][mt], 0, 0, 0);
#pragma unroll
    for (int ct = 0; ct < 4; ++ct) wcur[ct] = wnxt[ct];
  }

  // ELU -> hs (wave writes cols colw..+64 of all rows; distinct bytes per wave)
#pragma unroll
  for (int ct = 0; ct < 4; ++ct)
#pragma unroll
    for (int mt = 0; mt < 4; ++mt)
#pragma unroll
      for (int r = 0; r < 4; ++r) {
        float pre = acc[ct][mt][r] + b1v[ct];
        float h = pre > 0.0f ? pre : (__expf(pre) - 1.0f);
        int row = mt * 16 + g * 4 + r;
        int cb = (colw + ct * 16 + c) * 2;
        *(bf16*)(hs + row * 512 + (cb ^ ((row & 7) << 4))) = (bf16)h;
      }
  __syncthreads();

#pragma unroll
  for (int ct = 0; ct < 4; ++ct)
#pragma unroll
    for (int mt = 0; mt < 4; ++mt) acc[ct][mt] = fz;

  // GEMM2: z = h @ W2^T ; same prefetch discipline
#pragma unroll
  for (int ct = 0; ct < 4; ++ct)
    wcur[ct] = *(const bf16x8*)(w2base + (size_t)ct * 16 * DDIM);
#pragma unroll
  for (int ks = 0; ks < 8; ++ks) {
    if (ks < 7) {
#pragma unroll
      for (int ct = 0; ct < 4; ++ct)
        wnxt[ct] = *(const bf16x8*)(w2base + (size_t)ct * 16 * DDIM + (ks + 1) * 32);
    }
    bf16x8 af[4];
#pragma unroll
    for (int mt = 0; mt < 4; ++mt)
      af[mt] = *(const bf16x8*)(hs + (mt * 16 + c) * 512 + ((ks * 64 + g * 16) ^ aswz));
#pragma unroll
    for (int ct = 0; ct < 4; ++ct)
#pragma unroll
      for (int mt = 0; mt < 4; ++mt)
        acc[ct][mt] = __builtin_amdgcn_mfma_f32_16x16x32_bf16(af[mt], wcur[ct], acc[ct][mt], 0, 0, 0);
#pragma unroll
    for (int ct = 0; ct < 4; ++ct) wcur[ct] = wnxt[ct];
  }

  // bias + per-wave row-norm partials (sum over this wave's 64 cols)
  float ss[4][4];                         // [mt][r]
#pragma unroll
  for (int mt = 0; mt < 4; ++mt)
#pragma unroll
    for (int r = 0; r < 4; ++r) ss[mt][r] = 0.f;
#pragma unroll
  for (int ct = 0; ct < 4; ++ct)
#pragma unroll
    for (int mt = 0; mt < 4; ++mt)
#pragma unroll
      for (int r = 0; r < 4; ++r) {
        float z = acc[ct][mt][r] + b2v[ct];
        acc[ct][mt][r] = z;
        ss[mt][r] += z * z;
      }
#pragma unroll
  for (int m = 1; m < 16; m <<= 1)
#pragma unroll
    for (int mt = 0; mt < 4; ++mt)
#pragma unroll
      for (int r = 0; r < 4; ++r) ss[mt][r] += __shfl_xor(ss[mt][r], m, 64);

  if (c == 0) {
#pragma unroll
    for (int mt = 0; mt < 4; ++mt)
#pragma unroll
      for (int r = 0; r < 4; ++r) sspart[w][mt * 16 + g * 4 + r] = ss[mt][r];
  }
  __syncthreads();

#pragma unroll
  for (int mt = 0; mt < 4; ++mt)
#pragma unroll
    for (int r = 0; r < 4; ++r) {
      int row = mt * 16 + g * 4 + r;
      float s = sspart[0][row] + sspart[1][row] + sspart[2][row] + sspart[3][row];
      float rinv = osc / sqrtf(s);
#pragma unroll
      for (int ct = 0; ct < 4; ++ct)
        out[(size_t)(r0 + row) * DDIM + colw + ct * 16 + c] = (bf16)(acc[ct][mt][r] * rinv);
    }
}

// ---------------- 128x256 tile LSE: r9 structure, 64x128 per wave ----------------
// grid (32, 64) natural raster (bx fastest: 32 blocks share one A panel).
// block 256 (4 waves, 2 row-halves x 2 col-halves of 64x128). LDS 48 KB
// single-buffered (A 16K | B 32K), same 2-barrier/kt discipline as r9.
// 12 b128 reads feed 32 MFMAs per sk (r9: 8 per 16) -> LDS-port time -25%.
// A is KAPPA-prescaled -> epilogue sum += exp2(acc); diag on bx == by>>1.
__global__ __launch_bounds__(256) void lse_kernel(
    const bf16* __restrict__ A, const bf16* __restrict__ B,
    float* __restrict__ partial, float* __restrict__ diagdot)
{
  __shared__ __align__(16) char lds[49152];

  const int tid  = threadIdx.x;
  const int lane = tid & 63;
  const int w    = tid >> 6;
  const int c    = lane & 15;
  const int g    = lane >> 4;
  const int brow = blockIdx.y * 128;
  const int bcol = blockIdx.x * 256;
  const int wrow = (w >> 1) * 64;
  const int wcol = (w & 1) * 128;

  f32x4 acc[4][8];
  const f32x4 fz = {0.f, 0.f, 0.f, 0.f};
#pragma unroll
  for (int i = 0; i < 4; ++i)
#pragma unroll
    for (int j = 0; j < 8; ++j) acc[i][j] = fz;

  for (int kt = 0; kt < 4; ++kt) {
    // stage A (128x64, 16KB) + B (256x64, 32KB); linear dest, inv-swizzled src
#pragma unroll
    for (int it = 0; it < 4; ++it) {
      int slot = it * 256 + tid;
      int row = slot >> 3, q = slot & 7;
      int col = kt * 64 + ((q ^ (row & 7)) * 8);
      __builtin_amdgcn_global_load_lds(AS1C(A + (size_t)(brow + row) * DDIM + col),
                                       AS3(lds + (it * 256 + w * 64) * 16), 16, 0, 0);
    }
#pragma unroll
    for (int it = 0; it < 8; ++it) {
      int slot = it * 256 + tid;
      int row = slot >> 3, q = slot & 7;
      int col = kt * 64 + ((q ^ (row & 7)) * 8);
      __builtin_amdgcn_global_load_lds(AS1C(B + (size_t)(bcol + row) * DDIM + col),
                                       AS3(lds + 16384 + (it * 256 + w * 64) * 16), 16, 0, 0);
    }
    __syncthreads();

    const char* As = lds;
    const char* Bs = lds + 16384;
#pragma unroll
    for (int sk = 0; sk < 2; ++sk) {
      bf16x8 af[4], bfv[8];
#pragma unroll
      for (int mt = 0; mt < 4; ++mt) {
        int rl = wrow + mt * 16 + c;
        af[mt] = *(const bf16x8*)(As + rl * 128 + ((sk * 64 + g * 16) ^ ((rl & 7) << 4)));
      }
#pragma unroll
      for (int ct = 0; ct < 8; ++ct) {
        int rl = wcol + ct * 16 + c;
        bfv[ct] = *(const bf16x8*)(Bs + rl * 128 + ((sk * 64 + g * 16) ^ ((rl & 7) << 4)));
      }
#pragma unroll
      for (int mt = 0; mt < 4; ++mt)
#pragma unroll
        for (int ct = 0; ct < 8; ++ct)
          acc[mt][ct] = __builtin_amdgcn_mfma_f32_16x16x32_bf16(af[mt], bfv[ct], acc[mt][ct], 0, 0, 0);
    }
    __syncthreads();
  }

  // diag: block covers rows [by*128,+128), cols [bx*256,+256); diagonal lives at
  // bx == by>>1, col_local = (by&1)*128 + row_local -> waves with (w&1)==(by&1),
  // ct = (w>>1)*4 + mt, lanes c == g*4+r.
  if ((int)blockIdx.x == (int)(blockIdx.y >> 1) && (w & 1) == (int)(blockIdx.y & 1)
      && (c >> 2) == g) {
#pragma unroll
    for (int mt = 0; mt < 4; ++mt) {
      f32x4 a = (w >> 1) ? acc[mt][4 + mt] : acc[mt][mt];
      int r = c & 3;
      float dv = (r == 0) ? a[0] : (r == 1) ? a[1] : (r == 2) ? a[2] : a[3];
      diagdot[brow + wrow + mt * 16 + c] = dv;
    }
  }

  // epilogue: exp2(acc), reduce per 64-col half (h = ct>>2), then over c-lanes
  float rs[2][4][4];
#pragma unroll
  for (int h = 0; h < 2; ++h)
#pragma unroll
    for (int mt = 0; mt < 4; ++mt)
#pragma unroll
      for (int r = 0; r < 4; ++r) rs[h][mt][r] = 0.f;
#pragma unroll
  for (int mt = 0; mt < 4; ++mt)
#pragma unroll
    for (int ct = 0; ct < 8; ++ct)
#pragma unroll
      for (int r = 0; r < 4; ++r)
        rs[ct >> 2][mt][r] += __builtin_amdgcn_exp2f(acc[mt][ct][r]);
#pragma unroll
  for (int m = 1; m < 16; m <<= 1)
#pragma unroll
    for (int h = 0; h < 2; ++h)
#pragma unroll
      for (int mt = 0; mt < 4; ++mt)
#pragma unroll
        for (int r = 0; r < 4; ++r) rs[h][mt][r] += __shfl_xor(rs[h][mt][r], m, 64);

  if (c == 0) {
    int cb = blockIdx.x * 4 + (w & 1) * 2;
#pragma unroll
    for (int h = 0; h < 2; ++h)
#pragma unroll
      for (int mt = 0; mt < 4; ++mt)
#pragma unroll
        for (int r = 0; r < 4; ++r) {
          int grow = brow + wrow + mt * 16 + g * 4 + r;
          partial[(size_t)grow * 128 + cb + h] = rs[h][mt][r];
        }
  }
}

// ---------------- per-row: sum 128 partials + log - diag; block sums ----------------
__global__ __launch_bounds__(256) void rowfinal_kernel(
    const float* __restrict__ partial, const float* __restrict__ diagdot,
    float* __restrict__ blocksum)
{
  int row = blockIdx.x * 256 + threadIdx.x;
  const f32x4* p = (const f32x4*)(partial + (size_t)row * 128);
  float s = 0.f;
#pragma unroll 8
  for (int i = 0; i < 32; ++i) {
    f32x4 v = p[i];
    s += (v[0] + v[1]) + (v[2] + v[3]);
  }
  // diagdot = kappa * s_ii ; s_ii * TAU_INV = diagdot * ln2
  float term = logf(s + EPS) - diagdot[row] * LN2;
#pragma unroll
  for (int m = 1; m < 64; m <<= 1) term += __shfl_xor(term, m, 64);
  __shared__ float part[4];
  if ((threadIdx.x & 63) == 0) part[threadIdx.x >> 6] = term;
  __syncthreads();
  if (threadIdx.x == 0) blocksum[blockIdx.x] = part[0] + part[1] + part[2] + part[3];
}

// ---------------- final mean over 32 block sums ----------------
__global__ __launch_bounds__(64) void final_kernel(const float* __restrict__ blocksum,
                                                   float* __restrict__ out)
{
  int tid = threadIdx.x;
  float s = tid < 32 ? blocksum[tid] : 0.f;
#pragma unroll
  for (int m = 1; m < 64; m <<= 1) s += __shfl_xor(s, m, 64);
  if (tid == 0) out[0] = s * (1.0f / NROWS);
}

extern "C" void kernel_launch(void* const* d_in, const int* in_sizes, int n_in,
                              void* d_out, int out_size, void* d_ws, size_t ws_size,
                              hipStream_t stream) {
  const float* z1  = (const float*)d_in[0];
  const float* z2  = (const float*)d_in[1];
  const float* W1c = (const float*)d_in[2];
  const float* b1c = (const float*)d_in[3];
  const float* W2c = (const float*)d_in[4];
  const float* b2c = (const float*)d_in[5];
  const float* W1k = (const float*)d_in[6];
  const float* b1k = (const float*)d_in[7];
  const float* W2k = (const float*)d_in[8];
  const float* b2k = (const float*)d_in[9];

  char* ws = (char*)d_ws;
  bf16*  aU       = (bf16*)(ws);                               // 4 MB
  bf16*  bU       = (bf16*)(ws + (size_t)4  * 1024 * 1024);    // 4 MB
  float* partial  = (float*)(ws + (size_t)8  * 1024 * 1024);   // 8192*128 f32 = 4 MB
  float* diagdot  = (float*)(ws + (size_t)12 * 1024 * 1024);   // 32 KB
  float* blocksum = (float*)(ws + (size_t)12 * 1024 * 1024 + 64 * 1024);
  bf16*  wq       = (bf16*)(ws + (size_t)13 * 1024 * 1024);    // 512 KB

  cast4_kernel<<<dim3(64, 4), 256, 0, stream>>>(W1c, W2c, W1k, W2k, wq);

  mlp_norm_kernel<<<dim3(NROWS / 64, 2), 256, 0, stream>>>(
      z1, z2, wq, b1c, b2c, b1k, b2k, aU, bU);

  lse_kernel<<<dim3(NROWS / 256, NROWS / 128), 256, 0, stream>>>(aU, bU, partial, diagdot);

  rowfinal_kernel<<<32, 256, 0, stream>>>(partial, diagdot, blocksum);
  final_kernel<<<1, 64, 0, stream>>>(blocksum, (float*)d_out);
}

// Round 13
// 78.993 us; speedup vs baseline: 1.3904x; 1.3904x over previous
//
#include <hip/hip_runtime.h>

typedef __bf16 bf16;
typedef __bf16 bf16x8 __attribute__((ext_vector_type(8)));
typedef __bf16 bf16x4v __attribute__((ext_vector_type(4)));
typedef float  f32x4  __attribute__((ext_vector_type(4)));

#define NROWS 8192
#define DDIM  256
#define TAU_INV 2.0f
#define KAPPA 2.8853900817779268f   // TAU_INV * log2(e): A pre-scale so exp(s/tau) = exp2(acc)
#define LN2 0.6931471805599453f
#define EPS 1e-8f

#define AS1C(p) ((const __attribute__((address_space(1))) void*)(p))
#define AS3(p)  ((__attribute__((address_space(3))) void*)(p))

static __device__ __forceinline__ bf16x8 cvt8(f32x4 a, f32x4 b) {
  bf16x8 o;
  o[0] = (bf16)a[0]; o[1] = (bf16)a[1]; o[2] = (bf16)a[2]; o[3] = (bf16)a[3];
  o[4] = (bf16)b[0]; o[5] = (bf16)b[1]; o[6] = (bf16)b[2]; o[7] = (bf16)b[3];
  return o;
}

// ------- fused cast + 2-layer MLP + row-normalize (ct-split, fp32 weights) -------
// grid (NROWS/64, 2), block 256 (4 waves). Wave w computes output cols
// [w*64, w*64+64) for ALL 64 rows. fp32 weight fragments loaded one ks ahead and
// converted in-register (global loads never sit directly in front of their MFMA).
__global__ __launch_bounds__(256, 1) void mlp_norm_kernel(
    const float* __restrict__ z1f, const float* __restrict__ z2f,
    const float* __restrict__ W1c, const float* __restrict__ b1c,
    const float* __restrict__ W2c, const float* __restrict__ b2c,
    const float* __restrict__ W1k, const float* __restrict__ b1k,
    const float* __restrict__ W2k, const float* __restrict__ b2k,
    bf16* __restrict__ outA, bf16* __restrict__ outB)
{
  const int view = blockIdx.y;
  const float* xf = view ? z2f : z1f;
  const float* w1 = view ? W1k : W1c;
  const float* w2 = view ? W2k : W2c;
  const float* b1 = view ? b1k : b1c;
  const float* b2 = view ? b2k : b2c;
  bf16* out = view ? outB : outA;
  const float osc = view ? 1.0f : KAPPA;

  __shared__ __align__(16) char xs[64 * 512];   // x rows, XOR-swizzled
  __shared__ __align__(16) char hs[64 * 512];   // h rows, XOR-swizzled
  __shared__ float sspart[4][64];

  const int tid  = threadIdx.x;
  const int lane = tid & 63;
  const int w    = tid >> 6;
  const int c    = lane & 15;
  const int g    = lane >> 4;
  const int r0   = blockIdx.x * 64;
  const int colw = w * 64;

  // fused cast of z: load f32, convert, swizzled ds_write
#pragma unroll
  for (int k = 0; k < 8; ++k) {
    int gid = k * 256 + tid;
    int row = gid >> 5, cg = gid & 31;
    const f32x4* p = (const f32x4*)(xf + (size_t)(r0 + row) * DDIM + cg * 8);
    *(bf16x8*)(xs + row * 512 + ((cg * 16) ^ ((row & 7) << 4))) = cvt8(p[0], p[1]);
  }
  __syncthreads();

  float b1v[4], b2v[4];
#pragma unroll
  for (int ct = 0; ct < 4; ++ct) {
    b1v[ct] = b1[colw + ct * 16 + c];
    b2v[ct] = b2[colw + ct * 16 + c];
  }

  const int aswz = (c & 7) << 4;
  const float* w1base = w1 + (size_t)(colw + c) * DDIM + g * 8;  // + ct*16*DDIM + ks*32
  const float* w2base = w2 + (size_t)(colw + c) * DDIM + g * 8;

  f32x4 acc[4][4];                        // [ct][mt]
  const f32x4 fz = {0.f, 0.f, 0.f, 0.f};
#pragma unroll
  for (int ct = 0; ct < 4; ++ct)
#pragma unroll
    for (int mt = 0; mt < 4; ++mt) acc[ct][mt] = fz;

  // GEMM1: h_pre = x @ W1^T ; fp32 weights prefetched one ks ahead
  bf16x8 wcur[4];
  f32x4 wf0[4], wf1[4];
#pragma unroll
  for (int ct = 0; ct < 4; ++ct) {
    const f32x4* p = (const f32x4*)(w1base + (size_t)ct * 16 * DDIM);
    wcur[ct] = cvt8(p[0], p[1]);
  }
#pragma unroll
  for (int ks = 0; ks < 8; ++ks) {
    if (ks < 7) {
#pragma unroll
      for (int ct = 0; ct < 4; ++ct) {
        const f32x4* p = (const f32x4*)(w1base + (size_t)ct * 16 * DDIM + (ks + 1) * 32);
        wf0[ct] = p[0]; wf1[ct] = p[1];
      }
    }
    bf16x8 af[4];
#pragma unroll
    for (int mt = 0; mt < 4; ++mt)
      af[mt] = *(const bf16x8*)(xs + (mt * 16 + c) * 512 + ((ks * 64 + g * 16) ^ aswz));
#pragma unroll
    for (int ct = 0; ct < 4; ++ct)
#pragma unroll
      for (int mt = 0; mt < 4; ++mt)
        acc[ct][mt] = __builtin_amdgcn_mfma_f32_16x16x32_bf16(af[mt], wcur[ct], acc[ct][mt], 0, 0, 0);
    if (ks < 7) {
#pragma unroll
      for (int ct = 0; ct < 4; ++ct) wcur[ct] = cvt8(wf0[ct], wf1[ct]);
    }
  }

  // ELU -> hs (wave writes cols colw..+64 of all rows; distinct bytes per wave)
#pragma unroll
  for (int ct = 0; ct < 4; ++ct)
#pragma unroll
    for (int mt = 0; mt < 4; ++mt)
#pragma unroll
      for (int r = 0; r < 4; ++r) {
        float pre = acc[ct][mt][r] + b1v[ct];
        float h = pre > 0.0f ? pre : (__expf(pre) - 1.0f);
        int row = mt * 16 + g * 4 + r;
        int cb = (colw + ct * 16 + c) * 2;
        *(bf16*)(hs + row * 512 + (cb ^ ((row & 7) << 4))) = (bf16)h;
      }
  __syncthreads();

#pragma unroll
  for (int ct = 0; ct < 4; ++ct)
#pragma unroll
    for (int mt = 0; mt < 4; ++mt) acc[ct][mt] = fz;

  // GEMM2: z = h @ W2^T ; same prefetch discipline
#pragma unroll
  for (int ct = 0; ct < 4; ++ct) {
    const f32x4* p = (const f32x4*)(w2base + (size_t)ct * 16 * DDIM);
    wcur[ct] = cvt8(p[0], p[1]);
  }
#pragma unroll
  for (int ks = 0; ks < 8; ++ks) {
    if (ks < 7) {
#pragma unroll
      for (int ct = 0; ct < 4; ++ct) {
        const f32x4* p = (const f32x4*)(w2base + (size_t)ct * 16 * DDIM + (ks + 1) * 32);
        wf0[ct] = p[0]; wf1[ct] = p[1];
      }
    }
    bf16x8 af[4];
#pragma unroll
    for (int mt = 0; mt < 4; ++mt)
      af[mt] = *(const bf16x8*)(hs + (mt * 16 + c) * 512 + ((ks * 64 + g * 16) ^ aswz));
#pragma unroll
    for (int ct = 0; ct < 4; ++ct)
#pragma unroll
      for (int mt = 0; mt < 4; ++mt)
        acc[ct][mt] = __builtin_amdgcn_mfma_f32_16x16x32_bf16(af[mt], wcur[ct], acc[ct][mt], 0, 0, 0);
    if (ks < 7) {
#pragma unroll
      for (int ct = 0; ct < 4; ++ct) wcur[ct] = cvt8(wf0[ct], wf1[ct]);
    }
  }

  // bias + per-wave row-norm partials (sum over this wave's 64 cols)
  float ss[4][4];                         // [mt][r]
#pragma unroll
  for (int mt = 0; mt < 4; ++mt)
#pragma unroll
    for (int r = 0; r < 4; ++r) ss[mt][r] = 0.f;
#pragma unroll
  for (int ct = 0; ct < 4; ++ct)
#pragma unroll
    for (int mt = 0; mt < 4; ++mt)
#pragma unroll
      for (int r = 0; r < 4; ++r) {
        float z = acc[ct][mt][r] + b2v[ct];
        acc[ct][mt][r] = z;
        ss[mt][r] += z * z;
      }
#pragma unroll
  for (int m = 1; m < 16; m <<= 1)
#pragma unroll
    for (int mt = 0; mt < 4; ++mt)
#pragma unroll
      for (int r = 0; r < 4; ++r) ss[mt][r] += __shfl_xor(ss[mt][r], m, 64);

  if (c == 0) {
#pragma unroll
    for (int mt = 0; mt < 4; ++mt)
#pragma unroll
      for (int r = 0; r < 4; ++r) sspart[w][mt * 16 + g * 4 + r] = ss[mt][r];
  }
  __syncthreads();

#pragma unroll
  for (int mt = 0; mt < 4; ++mt)
#pragma unroll
    for (int r = 0; r < 4; ++r) {
      int row = mt * 16 + g * 4 + r;
      float s = sspart[0][row] + sspart[1][row] + sspart[2][row] + sspart[3][row];
      float rinv = osc / sqrtf(s);
#pragma unroll
      for (int ct = 0; ct < 4; ++ct)
        out[(size_t)(r0 + row) * DDIM + colw + ct * 16 + c] = (bf16)(acc[ct][mt][r] * rinv);
    }
}

// ---------------- 128x128 tile LSE (r9-proven, byte-identical) ----------------
// grid (64, 64), block 256 (4 waves, 2x2 of 64x64). LDS 32 KB single-buffered.
// A is KAPPA-prescaled -> epilogue sum += exp2(acc); diag extracted on bx==by.
__global__ __launch_bounds__(256, 2) void lse_kernel(
    const bf16* __restrict__ A, const bf16* __restrict__ B,
    float* __restrict__ partial, float* __restrict__ diagdot)
{
  __shared__ __align__(16) char As[128 * 128];  // 128 rows x 64 bf16, swizzled
  __shared__ __align__(16) char Bs[128 * 128];

  const int tid  = threadIdx.x;
  const int lane = tid & 63;
  const int w    = tid >> 6;
  const int c    = lane & 15;
  const int g    = lane >> 4;
  const int brow = blockIdx.y * 128;
  const int bcol = blockIdx.x * 128;
  const int wrow = (w >> 1) * 64;
  const int wcol = (w & 1) * 64;

  f32x4 acc[4][4];
  const f32x4 fz = {0.f, 0.f, 0.f, 0.f};
#pragma unroll
  for (int i = 0; i < 4; ++i)
#pragma unroll
    for (int j = 0; j < 4; ++j) acc[i][j] = fz;

  for (int kt = 0; kt < 4; ++kt) {
#pragma unroll
    for (int it = 0; it < 4; ++it) {
      int slot = it * 256 + tid;
      int row = slot >> 3, q = slot & 7;
      int col = kt * 64 + ((q ^ (row & 7)) * 8);
      __builtin_amdgcn_global_load_lds(AS1C(A + (size_t)(brow + row) * DDIM + col),
                                       AS3(As + (it * 256 + w * 64) * 16), 16, 0, 0);
      __builtin_amdgcn_global_load_lds(AS1C(B + (size_t)(bcol + row) * DDIM + col),
                                       AS3(Bs + (it * 256 + w * 64) * 16), 16, 0, 0);
    }
    __syncthreads();
#pragma unroll
    for (int sk = 0; sk < 2; ++sk) {
      bf16x8 af[4], bfv[4];
#pragma unroll
      for (int mt = 0; mt < 4; ++mt) {
        int rl = wrow + mt * 16 + c;
        af[mt] = *(const bf16x8*)(As + rl * 128 + ((sk * 64 + g * 16) ^ ((rl & 7) << 4)));
      }
#pragma unroll
      for (int ct = 0; ct < 4; ++ct) {
        int rl = wcol + ct * 16 + c;
        bfv[ct] = *(const bf16x8*)(Bs + rl * 128 + ((sk * 64 + g * 16) ^ ((rl & 7) << 4)));
      }
#pragma unroll
      for (int mt = 0; mt < 4; ++mt)
#pragma unroll
        for (int ct = 0; ct < 4; ++ct)
          acc[mt][ct] = __builtin_amdgcn_mfma_f32_16x16x32_bf16(af[mt], bfv[ct], acc[mt][ct], 0, 0, 0);
    }
    __syncthreads();
  }

  // diag: bx==by blocks, waves 0/3 (wrow==wcol), tiles ct==mt, lanes c==g*4+r
  if (blockIdx.x == blockIdx.y && (w == 0 || w == 3) && (c >> 2) == g) {
#pragma unroll
    for (int mt = 0; mt < 4; ++mt) {
      f32x4 a = acc[mt][mt];
      int r = c & 3;
      float dv = (r == 0) ? a[0] : (r == 1) ? a[1] : (r == 2) ? a[2] : a[3];
      diagdot[brow + wrow + mt * 16 + c] = dv;
    }
  }

  // epilogue: exp2(acc) (A pre-scaled by KAPPA), reduce over this wave's 64 cols
  float rs[4][4];
#pragma unroll
  for (int mt = 0; mt < 4; ++mt)
#pragma unroll
    for (int r = 0; r < 4; ++r) rs[mt][r] = 0.f;
#pragma unroll
  for (int mt = 0; mt < 4; ++mt)
#pragma unroll
    for (int ct = 0; ct < 4; ++ct)
#pragma unroll
      for (int r = 0; r < 4; ++r) rs[mt][r] += __builtin_amdgcn_exp2f(acc[mt][ct][r]);
#pragma unroll
  for (int m = 1; m < 16; m <<= 1)
#pragma unroll
    for (int mt = 0; mt < 4; ++mt)
#pragma unroll
      for (int r = 0; r < 4; ++r) rs[mt][r] += __shfl_xor(rs[mt][r], m, 64);

  if (c == 0) {
    int cb2 = blockIdx.x * 2 + (w & 1);
#pragma unroll
    for (int mt = 0; mt < 4; ++mt)
#pragma unroll
      for (int r = 0; r < 4; ++r) {
        int grow = brow + wrow + mt * 16 + g * 4 + r;
        partial[(size_t)grow * 128 + cb2] = rs[mt][r];
      }
  }
}

// ------- per-row: sum 128 partials + log - diag; 4 threads/row, block sums -------
// grid 128, block 256: 4 threads per row, each 8 f32x4; pair-combine via shfl.
__global__ __launch_bounds__(256) void rowfinal_kernel(
    const float* __restrict__ partial, const float* __restrict__ diagdot,
    float* __restrict__ blocksum)
{
  int gid = blockIdx.x * 256 + threadIdx.x;
  int row = gid >> 2, q = gid & 3;
  const f32x4* p = (const f32x4*)(partial + (size_t)row * 128 + q * 32);
  float s = 0.f;
#pragma unroll
  for (int i = 0; i < 8; ++i) {
    f32x4 v = p[i];
    s += (v[0] + v[1]) + (v[2] + v[3]);
  }
  s += __shfl_xor(s, 1, 64);
  s += __shfl_xor(s, 2, 64);
  // diagdot = kappa * s_ii ; s_ii * TAU_INV = diagdot * ln2
  float term = (q == 0) ? (logf(s + EPS) - diagdot[row] * LN2) : 0.f;
#pragma unroll
  for (int m = 1; m < 64; m <<= 1) term += __shfl_xor(term, m, 64);
  __shared__ float part[4];
  if ((threadIdx.x & 63) == 0) part[threadIdx.x >> 6] = term;
  __syncthreads();
  if (threadIdx.x == 0) blocksum[blockIdx.x] = part[0] + part[1] + part[2] + part[3];
}

// ---------------- final mean over 128 block sums ----------------
__global__ __launch_bounds__(128) void final_kernel(const float* __restrict__ blocksum,
                                                    float* __restrict__ out)
{
  int tid = threadIdx.x;
  float s = blocksum[tid];
#pragma unroll
  for (int m = 1; m < 64; m <<= 1) s += __shfl_xor(s, m, 64);
  __shared__ float p[2];
  if ((tid & 63) == 0) p[tid >> 6] = s;
  __syncthreads();
  if (tid == 0) out[0] = (p[0] + p[1]) * (1.0f / NROWS);
}

extern "C" void kernel_launch(void* const* d_in, const int* in_sizes, int n_in,
                              void* d_out, int out_size, void* d_ws, size_t ws_size,
                              hipStream_t stream) {
  const float* z1  = (const float*)d_in[0];
  const float* z2  = (const float*)d_in[1];
  const float* W1c = (const float*)d_in[2];
  const float* b1c = (const float*)d_in[3];
  const float* W2c = (const float*)d_in[4];
  const float* b2c = (const float*)d_in[5];
  const float* W1k = (const float*)d_in[6];
  const float* b1k = (const float*)d_in[7];
  const float* W2k = (const float*)d_in[8];
  const float* b2k = (const float*)d_in[9];

  char* ws = (char*)d_ws;
  bf16*  aU       = (bf16*)(ws);                               // 4 MB
  bf16*  bU       = (bf16*)(ws + (size_t)4  * 1024 * 1024);    // 4 MB
  float* partial  = (float*)(ws + (size_t)8  * 1024 * 1024);   // 8192*128 f32 = 4 MB
  float* diagdot  = (float*)(ws + (size_t)12 * 1024 * 1024);   // 32 KB
  float* blocksum = (float*)(ws + (size_t)12 * 1024 * 1024 + 64 * 1024);

  mlp_norm_kernel<<<dim3(NROWS / 64, 2), 256, 0, stream>>>(
      z1, z2, W1c, b1c, W2c, b2c, W1k, b1k, W2k, b2k, aU, bU);

  lse_kernel<<<dim3(NROWS / 128, NROWS / 128), 256, 0, stream>>>(aU, bU, partial, diagdot);

  rowfinal_kernel<<<128, 256, 0, stream>>>(partial, diagdot, blocksum);
  final_kernel<<<1, 128, 0, stream>>>(blocksum, (float*)d_out);
}

// Round 14
// 75.936 us; speedup vs baseline: 1.4464x; 1.0403x over previous
//
#include <hip/hip_runtime.h>

typedef __bf16 bf16;
typedef __bf16 bf16x8 __attribute__((ext_vector_type(8)));
typedef __bf16 bf16x4v __attribute__((ext_vector_type(4)));
typedef float  f32x4  __attribute__((ext_vector_type(4)));

#define NROWS 8192
#define DDIM  256
#define TAU_INV 2.0f
#define KAPPA 2.8853900817779268f   // TAU_INV * log2(e): A pre-scale so exp(s/tau) = exp2(acc)
#define LN2 0.6931471805599453f
#define EPS 1e-8f

#define AS1C(p) ((const __attribute__((address_space(1))) void*)(p))
#define AS3(p)  ((__attribute__((address_space(3))) void*)(p))

static __device__ __forceinline__ bf16x8 cvt8(f32x4 a, f32x4 b) {
  bf16x8 o;
  o[0] = (bf16)a[0]; o[1] = (bf16)a[1]; o[2] = (bf16)a[2]; o[3] = (bf16)a[3];
  o[4] = (bf16)b[0]; o[5] = (bf16)b[1]; o[6] = (bf16)b[2]; o[7] = (bf16)b[3];
  return o;
}

// ---------------- cast 4 weight matrices fp32 -> bf16 ----------------
__global__ __launch_bounds__(256) void cast4_kernel(
    const float* __restrict__ s0, const float* __restrict__ s1,
    const float* __restrict__ s2, const float* __restrict__ s3,
    bf16* __restrict__ dst) {
  const float* s = blockIdx.y == 0 ? s0 : blockIdx.y == 1 ? s1 : blockIdx.y == 2 ? s2 : s3;
  bf16* d = dst + (size_t)blockIdx.y * 65536;
  int i = blockIdx.x * 256 + threadIdx.x;
  f32x4 v = ((const f32x4*)s)[i];
  bf16x4v o;
  o[0] = (bf16)v[0]; o[1] = (bf16)v[1]; o[2] = (bf16)v[2]; o[3] = (bf16)v[3];
  ((bf16x4v*)d)[i] = o;
}

// ------- fused cast(z) + 2-layer MLP + row-normalize (8-wave ct-split) -------
// grid (NROWS/64, 2), block 512 (8 waves -> 2 waves/SIMD at 1 block/CU).
// Wave w computes output cols [w*32, w*32+32) for ALL 64 rows; bf16 weight
// fragments register-prefetched one ks ahead (r12-proven discipline).
__global__ __launch_bounds__(512, 1) void mlp_norm_kernel(
    const float* __restrict__ z1f, const float* __restrict__ z2f,
    const bf16* __restrict__ wq,
    const float* __restrict__ b1c, const float* __restrict__ b2c,
    const float* __restrict__ b1k, const float* __restrict__ b2k,
    bf16* __restrict__ outA, bf16* __restrict__ outB)
{
  const int view = blockIdx.y;
  const float* xf = view ? z2f : z1f;
  const bf16*  w1 = wq + (size_t)view * 131072;
  const bf16*  w2 = w1 + 65536;
  const float* b1 = view ? b1k : b1c;
  const float* b2 = view ? b2k : b2c;
  bf16* out = view ? outB : outA;
  const float osc = view ? 1.0f : KAPPA;

  __shared__ __align__(16) char xs[64 * 512];   // x rows, XOR-swizzled
  __shared__ __align__(16) char hs[64 * 512];   // h rows, XOR-swizzled
  __shared__ float sspart[8][64];

  const int tid  = threadIdx.x;
  const int lane = tid & 63;
  const int w    = tid >> 6;          // 0..7
  const int c    = lane & 15;
  const int g    = lane >> 4;
  const int r0   = blockIdx.x * 64;
  const int colw = w * 32;

  // fused cast of z: 64 rows x 256 cols, 2048 groups of 8, 512 threads -> 4 iters
#pragma unroll
  for (int k = 0; k < 4; ++k) {
    int gid = k * 512 + tid;
    int row = gid >> 5, cg = gid & 31;
    const f32x4* p = (const f32x4*)(xf + (size_t)(r0 + row) * DDIM + cg * 8);
    *(bf16x8*)(xs + row * 512 + ((cg * 16) ^ ((row & 7) << 4))) = cvt8(p[0], p[1]);
  }
  __syncthreads();

  float b1v[2], b2v[2];
#pragma unroll
  for (int ct = 0; ct < 2; ++ct) {
    b1v[ct] = b1[colw + ct * 16 + c];
    b2v[ct] = b2[colw + ct * 16 + c];
  }

  const int aswz = (c & 7) << 4;
  const bf16* w1base = w1 + (size_t)(colw + c) * DDIM + g * 8;  // + ct*16*DDIM + ks*32
  const bf16* w2base = w2 + (size_t)(colw + c) * DDIM + g * 8;

  f32x4 acc[2][4];                        // [ct][mt]
  const f32x4 fz = {0.f, 0.f, 0.f, 0.f};
#pragma unroll
  for (int ct = 0; ct < 2; ++ct)
#pragma unroll
    for (int mt = 0; mt < 4; ++mt) acc[ct][mt] = fz;

  // GEMM1: h_pre = x @ W1^T ; weights prefetched one ks ahead
  bf16x8 wcur[2], wnxt[2];
#pragma unroll
  for (int ct = 0; ct < 2; ++ct)
    wcur[ct] = *(const bf16x8*)(w1base + (size_t)ct * 16 * DDIM);
#pragma unroll
  for (int ks = 0; ks < 8; ++ks) {
    if (ks < 7) {
#pragma unroll
      for (int ct = 0; ct < 2; ++ct)
        wnxt[ct] = *(const bf16x8*)(w1base + (size_t)ct * 16 * DDIM + (ks + 1) * 32);
    }
    bf16x8 af[4];
#pragma unroll
    for (int mt = 0; mt < 4; ++mt)
      af[mt] = *(const bf16x8*)(xs + (mt * 16 + c) * 512 + ((ks * 64 + g * 16) ^ aswz));
#pragma unroll
    for (int ct = 0; ct < 2; ++ct)
#pragma unroll
      for (int mt = 0; mt < 4; ++mt)
        acc[ct][mt] = __builtin_amdgcn_mfma_f32_16x16x32_bf16(af[mt], wcur[ct], acc[ct][mt], 0, 0, 0);
#pragma unroll
    for (int ct = 0; ct < 2; ++ct) wcur[ct] = wnxt[ct];
  }

  // ELU -> hs (wave writes cols colw..+32 of all rows; distinct bytes per wave)
#pragma unroll
  for (int ct = 0; ct < 2; ++ct)
#pragma unroll
    for (int mt = 0; mt < 4; ++mt)
#pragma unroll
      for (int r = 0; r < 4; ++r) {
        float pre = acc[ct][mt][r] + b1v[ct];
        float h = pre > 0.0f ? pre : (__expf(pre) - 1.0f);
        int row = mt * 16 + g * 4 + r;
        int cb = (colw + ct * 16 + c) * 2;
        *(bf16*)(hs + row * 512 + (cb ^ ((row & 7) << 4))) = (bf16)h;
      }
  __syncthreads();

#pragma unroll
  for (int ct = 0; ct < 2; ++ct)
#pragma unroll
    for (int mt = 0; mt < 4; ++mt) acc[ct][mt] = fz;

  // GEMM2: z = h @ W2^T ; same prefetch discipline
#pragma unroll
  for (int ct = 0; ct < 2; ++ct)
    wcur[ct] = *(const bf16x8*)(w2base + (size_t)ct * 16 * DDIM);
#pragma unroll
  for (int ks = 0; ks < 8; ++ks) {
    if (ks < 7) {
#pragma unroll
      for (int ct = 0; ct < 2; ++ct)
        wnxt[ct] = *(const bf16x8*)(w2base + (size_t)ct * 16 * DDIM + (ks + 1) * 32);
    }
    bf16x8 af[4];
#pragma unroll
    for (int mt = 0; mt < 4; ++mt)
      af[mt] = *(const bf16x8*)(hs + (mt * 16 + c) * 512 + ((ks * 64 + g * 16) ^ aswz));
#pragma unroll
    for (int ct = 0; ct < 2; ++ct)
#pragma unroll
      for (int mt = 0; mt < 4; ++mt)
        acc[ct][mt] = __builtin_amdgcn_mfma_f32_16x16x32_bf16(af[mt], wcur[ct], acc[ct][mt], 0, 0, 0);
#pragma unroll
    for (int ct = 0; ct < 2; ++ct) wcur[ct] = wnxt[ct];
  }

  // bias + per-wave row-norm partials (sum over this wave's 32 cols)
  float ss[4][4];                         // [mt][r]
#pragma unroll
  for (int mt = 0; mt < 4; ++mt)
#pragma unroll
    for (int r = 0; r < 4; ++r) ss[mt][r] = 0.f;
#pragma unroll
  for (int ct = 0; ct < 2; ++ct)
#pragma unroll
    for (int mt = 0; mt < 4; ++mt)
#pragma unroll
      for (int r = 0; r < 4; ++r) {
        float z = acc[ct][mt][r] + b2v[ct];
        acc[ct][mt][r] = z;
        ss[mt][r] += z * z;
      }
#pragma unroll
  for (int m = 1; m < 16; m <<= 1)
#pragma unroll
    for (int mt = 0; mt < 4; ++mt)
#pragma unroll
      for (int r = 0; r < 4; ++r) ss[mt][r] += __shfl_xor(ss[mt][r], m, 64);

  if (c == 0) {
#pragma unroll
    for (int mt = 0; mt < 4; ++mt)
#pragma unroll
      for (int r = 0; r < 4; ++r) sspart[w][mt * 16 + g * 4 + r] = ss[mt][r];
  }
  __syncthreads();

#pragma unroll
  for (int mt = 0; mt < 4; ++mt)
#pragma unroll
    for (int r = 0; r < 4; ++r) {
      int row = mt * 16 + g * 4 + r;
      float s = (sspart[0][row] + sspart[1][row]) + (sspart[2][row] + sspart[3][row])
              + (sspart[4][row] + sspart[5][row]) + (sspart[6][row] + sspart[7][row]);
      float rinv = osc / sqrtf(s);
#pragma unroll
      for (int ct = 0; ct < 2; ++ct)
        out[(size_t)(r0 + row) * DDIM + colw + ct * 16 + c] = (bf16)(acc[ct][mt][r] * rinv);
    }
}

// ---------------- 128x128 tile LSE (r9-proven, byte-identical) ----------------
// grid (64, 64), block 256 (4 waves, 2x2 of 64x64). LDS 32 KB single-buffered.
// A is KAPPA-prescaled -> epilogue sum += exp2(acc); diag extracted on bx==by.
__global__ __launch_bounds__(256, 2) void lse_kernel(
    const bf16* __restrict__ A, const bf16* __restrict__ B,
    float* __restrict__ partial, float* __restrict__ diagdot)
{
  __shared__ __align__(16) char As[128 * 128];  // 128 rows x 64 bf16, swizzled
  __shared__ __align__(16) char Bs[128 * 128];

  const int tid  = threadIdx.x;
  const int lane = tid & 63;
  const int w    = tid >> 6;
  const int c    = lane & 15;
  const int g    = lane >> 4;
  const int brow = blockIdx.y * 128;
  const int bcol = blockIdx.x * 128;
  const int wrow = (w >> 1) * 64;
  const int wcol = (w & 1) * 64;

  f32x4 acc[4][4];
  const f32x4 fz = {0.f, 0.f, 0.f, 0.f};
#pragma unroll
  for (int i = 0; i < 4; ++i)
#pragma unroll
    for (int j = 0; j < 4; ++j) acc[i][j] = fz;

  for (int kt = 0; kt < 4; ++kt) {
#pragma unroll
    for (int it = 0; it < 4; ++it) {
      int slot = it * 256 + tid;
      int row = slot >> 3, q = slot & 7;
      int col = kt * 64 + ((q ^ (row & 7)) * 8);
      __builtin_amdgcn_global_load_lds(AS1C(A + (size_t)(brow + row) * DDIM + col),
                                       AS3(As + (it * 256 + w * 64) * 16), 16, 0, 0);
      __builtin_amdgcn_global_load_lds(AS1C(B + (size_t)(bcol + row) * DDIM + col),
                                       AS3(Bs + (it * 256 + w * 64) * 16), 16, 0, 0);
    }
    __syncthreads();
#pragma unroll
    for (int sk = 0; sk < 2; ++sk) {
      bf16x8 af[4], bfv[4];
#pragma unroll
      for (int mt = 0; mt < 4; ++mt) {
        int rl = wrow + mt * 16 + c;
        af[mt] = *(const bf16x8*)(As + rl * 128 + ((sk * 64 + g * 16) ^ ((rl & 7) << 4)));
      }
#pragma unroll
      for (int ct = 0; ct < 4; ++ct) {
        int rl = wcol + ct * 16 + c;
        bfv[ct] = *(const bf16x8*)(Bs + rl * 128 + ((sk * 64 + g * 16) ^ ((rl & 7) << 4)));
      }
#pragma unroll
      for (int mt = 0; mt < 4; ++mt)
#pragma unroll
        for (int ct = 0; ct < 4; ++ct)
          acc[mt][ct] = __builtin_amdgcn_mfma_f32_16x16x32_bf16(af[mt], bfv[ct], acc[mt][ct], 0, 0, 0);
    }
    __syncthreads();
  }

  // diag: bx==by blocks, waves 0/3 (wrow==wcol), tiles ct==mt, lanes c==g*4+r
  if (blockIdx.x == blockIdx.y && (w == 0 || w == 3) && (c >> 2) == g) {
#pragma unroll
    for (int mt = 0; mt < 4; ++mt) {
      f32x4 a = acc[mt][mt];
      int r = c & 3;
      float dv = (r == 0) ? a[0] : (r == 1) ? a[1] : (r == 2) ? a[2] : a[3];
      diagdot[brow + wrow + mt * 16 + c] = dv;
    }
  }

  // epilogue: exp2(acc) (A pre-scaled by KAPPA), reduce over this wave's 64 cols
  float rs[4][4];
#pragma unroll
  for (int mt = 0; mt < 4; ++mt)
#pragma unroll
    for (int r = 0; r < 4; ++r) rs[mt][r] = 0.f;
#pragma unroll
  for (int mt = 0; mt < 4; ++mt)
#pragma unroll
    for (int ct = 0; ct < 4; ++ct)
#pragma unroll
      for (int r = 0; r < 4; ++r) rs[mt][r] += __builtin_amdgcn_exp2f(acc[mt][ct][r]);
#pragma unroll
  for (int m = 1; m < 16; m <<= 1)
#pragma unroll
    for (int mt = 0; mt < 4; ++mt)
#pragma unroll
      for (int r = 0; r < 4; ++r) rs[mt][r] += __shfl_xor(rs[mt][r], m, 64);

  if (c == 0) {
    int cb2 = blockIdx.x * 2 + (w & 1);
#pragma unroll
    for (int mt = 0; mt < 4; ++mt)
#pragma unroll
      for (int r = 0; r < 4; ++r) {
        int grow = brow + wrow + mt * 16 + g * 4 + r;
        partial[(size_t)grow * 128 + cb2] = rs[mt][r];
      }
  }
}

// ------- per-row: sum 128 partials + log - diag; 4 threads/row, block sums -------
__global__ __launch_bounds__(256) void rowfinal_kernel(
    const float* __restrict__ partial, const float* __restrict__ diagdot,
    float* __restrict__ blocksum)
{
  int gid = blockIdx.x * 256 + threadIdx.x;
  int row = gid >> 2, q = gid & 3;
  const f32x4* p = (const f32x4*)(partial + (size_t)row * 128 + q * 32);
  float s = 0.f;
#pragma unroll
  for (int i = 0; i < 8; ++i) {
    f32x4 v = p[i];
    s += (v[0] + v[1]) + (v[2] + v[3]);
  }
  s += __shfl_xor(s, 1, 64);
  s += __shfl_xor(s, 2, 64);
  // diagdot = kappa * s_ii ; s_ii * TAU_INV = diagdot * ln2
  float term = (q == 0) ? (logf(s + EPS) - diagdot[row] * LN2) : 0.f;
#pragma unroll
  for (int m = 1; m < 64; m <<= 1) term += __shfl_xor(term, m, 64);
  __shared__ float part[4];
  if ((threadIdx.x & 63) == 0) part[threadIdx.x >> 6] = term;
  __syncthreads();
  if (threadIdx.x == 0) blocksum[blockIdx.x] = part[0] + part[1] + part[2] + part[3];
}

// ---------------- final mean over 128 block sums ----------------
__global__ __launch_bounds__(128) void final_kernel(const float* __restrict__ blocksum,
                                                    float* __restrict__ out)
{
  int tid = threadIdx.x;
  float s = blocksum[tid];
#pragma unroll
  for (int m = 1; m < 64; m <<= 1) s += __shfl_xor(s, m, 64);
  __shared__ float p[2];
  if ((tid & 63) == 0) p[tid >> 6] = s;
  __syncthreads();
  if (tid == 0) out[0] = (p[0] + p[1]) * (1.0f / NROWS);
}

extern "C" void kernel_launch(void* const* d_in, const int* in_sizes, int n_in,
                              void* d_out, int out_size, void* d_ws, size_t ws_size,
                              hipStream_t stream) {
  const float* z1  = (const float*)d_in[0];
  const float* z2  = (const float*)d_in[1];
  const float* W1c = (const float*)d_in[2];
  const float* b1c = (const float*)d_in[3];
  const float* W2c = (const float*)d_in[4];
  const float* b2c = (const float*)d_in[5];
  const float* W1k = (const float*)d_in[6];
  const float* b1k = (const float*)d_in[7];
  const float* W2k = (const float*)d_in[8];
  const float* b2k = (const float*)d_in[9];

  char* ws = (char*)d_ws;
  bf16*  aU       = (bf16*)(ws);                               // 4 MB
  bf16*  bU       = (bf16*)(ws + (size_t)4  * 1024 * 1024);    // 4 MB
  float* partial  = (float*)(ws + (size_t)8  * 1024 * 1024);   // 8192*128 f32 = 4 MB
  float* diagdot  = (float*)(ws + (size_t)12 * 1024 * 1024);   // 32 KB
  float* blocksum = (float*)(ws + (size_t)12 * 1024 * 1024 + 64 * 1024);
  bf16*  wq       = (bf16*)(ws + (size_t)13 * 1024 * 1024);    // 512 KB

  cast4_kernel<<<dim3(64, 4), 256, 0, stream>>>(W1c, W2c, W1k, W2k, wq);

  mlp_norm_kernel<<<dim3(NROWS / 64, 2), 512, 0, stream>>>(
      z1, z2, wq, b1c, b2c, b1k, b2k, aU, bU);

  lse_kernel<<<dim3(NROWS / 128, NROWS / 128), 256, 0, stream>>>(aU, bU, partial, diagdot);

  rowfinal_kernel<<<128, 256, 0, stream>>>(partial, diagdot, blocksum);
  final_kernel<<<1, 128, 0, stream>>>(blocksum, (float*)d_out);
}